// Round 9
// baseline (500.812 us; speedup 1.0000x reference)
//
#include <hip/hip_runtime.h>
#include <cstdint>

#define N_NODES 40000
#define N_EDGES 400000
#define DIN 256
#define DHID 128
#define NG 256
#define NHEAD 4
#define ETOT (N_EDGES + N_NODES)

typedef __attribute__((ext_vector_type(8))) short short8;
typedef __attribute__((ext_vector_type(8))) unsigned short bfx8;
typedef __attribute__((ext_vector_type(4))) unsigned short bfx4;
typedef __attribute__((ext_vector_type(4))) float floatx4;

static __device__ __forceinline__ unsigned short f2bf(float f) {
    unsigned u = __float_as_uint(f);
    unsigned r = (u + 0x7FFFu + ((u >> 16) & 1u)) >> 16;
    return (unsigned short)r;
}
static __device__ __forceinline__ float bf2f(unsigned short s) {
    return __uint_as_float((unsigned)s << 16);
}

// ---------------- fused prep: edge count + 3 weight transposes ----------------
// block ranges: [0,1719) count, [1719,2231) W1t, [2231,2487) W2t, [2487,2551) W3t

#define NB_CNT 1719
#define NB_W1  512
#define NB_W2  256
#define NB_W3  64

__global__ void prep_kernel(const int* __restrict__ dst, int* __restrict__ deg,
                            const float* __restrict__ W1, unsigned short* __restrict__ W1t,
                            const float* __restrict__ W2, unsigned short* __restrict__ W2t,
                            const float* __restrict__ W3, unsigned short* __restrict__ W3t) {
    int b = blockIdx.x;
    if (b < NB_CNT) {
        int i = b * 256 + threadIdx.x;
        if (i >= ETOT) return;
        int d = (i < N_EDGES) ? dst[i] : (i - N_EDGES);
        atomicAdd(&deg[d], 1);
    } else if (b < NB_CNT + NB_W1) {
        int i = (b - NB_CNT) * 256 + threadIdx.x;       // i < 256*512
        int k = i >> 9, n = i & 511;                     // W1[k*512+n]
        W1t[(size_t)n * 256 + k] = f2bf(W1[i]);
    } else if (b < NB_CNT + NB_W1 + NB_W2) {
        int i = (b - NB_CNT - NB_W1) * 256 + threadIdx.x; // 128*512
        int k = i >> 9, n = i & 511;
        W2t[(size_t)n * 128 + k] = f2bf(W2[i]);
    } else {
        int i = (b - NB_CNT - NB_W1 - NB_W2) * 256 + threadIdx.x; // 128*128
        int k = i >> 7, n = i & 127;
        W3t[(size_t)n * 128 + k] = f2bf(W3[i]);
    }
}

// ---------------- coalesced two-phase scan ----------------
// 16 waves; wave w owns contiguous chunk [w*2560, (w+1)*2560); lane-strided
// coalesced loads into registers; phase 1 wave totals, phase 2 running scan.

__global__ __launch_bounds__(1024) void scan_kernel(const int* __restrict__ deg,
                                                    int* __restrict__ offs,
                                                    int* __restrict__ cursor) {
    const int IT = 40;                     // 64 lanes * 40 = 2560 per wave
    __shared__ int wsum[16];
    int t = threadIdx.x;
    int lane = t & 63, wv = t >> 6;
    int base = wv * 2560;
    int vals[IT];
    int lsum = 0;
#pragma unroll
    for (int i = 0; i < IT; i++) {
        int idx = base + i * 64 + lane;
        int v = (idx < N_NODES) ? deg[idx] : 0;
        vals[i] = v;
        lsum += v;
    }
#pragma unroll
    for (int m = 32; m >= 1; m >>= 1) lsum += __shfl_xor(lsum, m, 64);
    if (lane == 0) wsum[wv] = lsum;
    __syncthreads();
    if (t == 0) {
        int c = 0;
#pragma unroll
        for (int i = 0; i < 16; i++) { int v = wsum[i]; wsum[i] = c; c += v; }
    }
    __syncthreads();
    int carry = wsum[wv];
#pragma unroll
    for (int i = 0; i < IT; i++) {
        int v = vals[i];
        int inc = v;
#pragma unroll
        for (int off = 1; off < 64; off <<= 1) {
            int n = __shfl_up(inc, off, 64);
            if (lane >= off) inc += n;
        }
        int tot = __shfl(inc, 63, 64);
        int idx = base + i * 64 + lane;
        if (idx < N_NODES) { int o = carry + inc - v; offs[idx] = o; cursor[idx] = o; }
        carry += tot;
    }
    if (t == 0) offs[N_NODES] = ETOT;
}

__global__ void fill_kernel(const int* __restrict__ src, const int* __restrict__ dst,
                            int* __restrict__ cursor, int* __restrict__ csr) {
    int i = blockIdx.x * 256 + threadIdx.x;
    if (i >= ETOT) return;
    int s, d;
    if (i < N_EDGES) { s = src[i]; d = dst[i]; } else { s = d = i - N_EDGES; }
    int pos = atomicAdd(&cursor[d], 1);
    csr[pos] = s;
}

// ---------------- MFMA GEMM, all SH heads per block + score epilogue ----------------
// C[M, SH*128] = A[M,K] * Bt^T. One block = 64 rows x all heads; A staged once
// per K-chunk (kills the per-head redundant A fetch). acc[SH][4][2].

template <int K, int SH, bool AF32>
__global__ __launch_bounds__(256) void mfma_gemm_kernel(const void* __restrict__ Aptr,
                                                        const unsigned short* __restrict__ Bt,
                                                        unsigned short* __restrict__ C,
                                                        const float* __restrict__ asrc,
                                                        const float* __restrict__ adst,
                                                        float* __restrict__ ssrc,
                                                        float* __restrict__ sdst) {
    constexpr int KC = 128;
    constexpr int KP = KC + 8;
    constexpr int NCOL = SH * 128;
    __shared__ alignas(16) unsigned short A_lds[64][KP];
    __shared__ alignas(16) unsigned short B_lds[128][KP];

    const int tid = threadIdx.x;
    const int lane = tid & 63, wave = tid >> 6;
    const int row0 = blockIdx.x * 64;
    const int cq = lane & 15, rq = lane >> 4;

    floatx4 acc[SH][4][2] = {};

    for (int k0 = 0; k0 < K; k0 += KC) {
        __syncthreads();   // guard A_lds/B_lds reuse (harmless on first iter)
#pragma unroll
        for (int r = 0; r < 4; r++) {
            int i = r * 256 + tid;
            int row = i >> 4, slot = i & 15;
            if constexpr (AF32) {
                const float* ap = (const float*)Aptr + (size_t)(row0 + row) * K + k0 + slot * 8;
                float4 u0 = *(const float4*)ap;
                float4 u1 = *(const float4*)(ap + 4);
                short8 v;
                v[0] = (short)f2bf(u0.x); v[1] = (short)f2bf(u0.y);
                v[2] = (short)f2bf(u0.z); v[3] = (short)f2bf(u0.w);
                v[4] = (short)f2bf(u1.x); v[5] = (short)f2bf(u1.y);
                v[6] = (short)f2bf(u1.z); v[7] = (short)f2bf(u1.w);
                *(short8*)&A_lds[row][slot * 8] = v;
            } else {
                const unsigned short* ap = (const unsigned short*)Aptr + (size_t)(row0 + row) * K + k0 + slot * 8;
                *(short8*)&A_lds[row][slot * 8] = *(const short8*)ap;
            }
        }
#pragma unroll
        for (int h = 0; h < SH; h++) {
            if (h) __syncthreads();   // protect B_lds from prior head's reads
#pragma unroll
            for (int r = 0; r < 8; r++) {
                int i = r * 256 + tid;
                int col = i >> 4, slot = i & 15;
                short8 v = *(const short8*)(Bt + (size_t)(h * 128 + col) * K + k0 + slot * 8);
                *(short8*)&B_lds[col][slot * 8] = v;
            }
            __syncthreads();
#pragma unroll
            for (int kk = 0; kk < KC; kk += 32) {
                short8 af[4], bfr[2];
#pragma unroll
                for (int i = 0; i < 4; i++)
                    af[i] = *(const short8*)&A_lds[i * 16 + cq][kk + rq * 8];
#pragma unroll
                for (int j = 0; j < 2; j++)
                    bfr[j] = *(const short8*)&B_lds[wave * 32 + j * 16 + cq][kk + rq * 8];
#pragma unroll
                for (int i = 0; i < 4; i++)
#pragma unroll
                    for (int j = 0; j < 2; j++)
                        acc[h][i][j] = __builtin_amdgcn_mfma_f32_16x16x32_bf16(af[i], bfr[j], acc[h][i][j], 0, 0, 0);
            }
        }
    }

    // C write (bf16), all heads
#pragma unroll
    for (int h = 0; h < SH; h++)
#pragma unroll
        for (int i = 0; i < 4; i++)
#pragma unroll
            for (int j = 0; j < 2; j++) {
                unsigned short* cp = C + (size_t)(row0 + i * 16 + rq * 4) * NCOL + h * 128 + wave * 32 + j * 16 + cq;
#pragma unroll
                for (int r = 0; r < 4; r++)
                    cp[(size_t)r * NCOL] = f2bf(acc[h][i][j][r]);
            }

    // ---- fused score epilogue (per head; sred/dred alias A_lds) ----
    float* sred = (float*)&A_lds[0][0];        // [4][64]
    float* dred = sred + 256;                  // [4][64]
#pragma unroll
    for (int h = 0; h < SH; h++) {
        const float* ah = asrc + h * 128;
        const float* dh = adst + h * 128;
        float a0 = ah[wave * 32 + cq], a1 = ah[wave * 32 + 16 + cq];
        float d0 = dh[wave * 32 + cq], d1 = dh[wave * 32 + 16 + cq];
        __syncthreads();
#pragma unroll
        for (int i = 0; i < 4; i++)
#pragma unroll
            for (int r = 0; r < 4; r++) {
                float ss = acc[h][i][0][r] * a0 + acc[h][i][1][r] * a1;
                float sd = acc[h][i][0][r] * d0 + acc[h][i][1][r] * d1;
#pragma unroll
                for (int m = 1; m <= 8; m <<= 1) {
                    ss += __shfl_xor(ss, m, 64);
                    sd += __shfl_xor(sd, m, 64);
                }
                if (cq == 0) {
                    int row = i * 16 + rq * 4 + r;
                    sred[wave * 64 + row] = ss;
                    dred[wave * 64 + row] = sd;
                }
            }
        __syncthreads();
        if (tid < 64) {
            float ss = sred[tid] + sred[64 + tid] + sred[128 + tid] + sred[192 + tid];
            float sd = dred[tid] + dred[64 + tid] + dred[128 + tid] + dred[192 + tid];
            ssrc[(size_t)(row0 + tid) * SH + h] = ss;
            sdst[(size_t)(row0 + tid) * SH + h] = sd;
        }
    }
}

// ---------------- fused softmax + aggregation, layer 1/2 (H=4) ----------------
// 1 wave/node, no barriers; inline logits from L2-resident ssrc4; wave-private
// LDS broadcast of alpha/src; 4-wide unrolled 1 KB-row gather.

__global__ __launch_bounds__(256) void agg4_kernel(const int* __restrict__ offs,
                                                   const int* __restrict__ csr,
                                                   const unsigned short* __restrict__ hbuf,
                                                   const float4* __restrict__ ssrc4,
                                                   const float4* __restrict__ sdst4,
                                                   const float* __restrict__ bias,
                                                   const float* __restrict__ bng,
                                                   const float* __restrict__ bnb,
                                                   const float* __restrict__ bnm,
                                                   const float* __restrict__ bnv,
                                                   unsigned short* __restrict__ outb) {
    __shared__ alignas(16) float aload[4][64][4];
    __shared__ int sload[4][64];

    int wave = threadIdx.x >> 6, lane = threadIdx.x & 63;
    int d = blockIdx.x * 4 + wave;
    int off = offs[d];
    int deg = offs[d + 1] - off;
    int hh = lane >> 4;
    float4 sdv = sdst4[d];
    float acc[8] = {};

    if (deg <= 64) {
        int sreg = 0;
        float4 ev;
        if (lane < deg) {
            sreg = csr[off + lane];
            float4 es = ssrc4[sreg];
            ev.x = es.x + sdv.x; ev.x = ev.x > 0.f ? ev.x : 0.2f * ev.x;
            ev.y = es.y + sdv.y; ev.y = ev.y > 0.f ? ev.y : 0.2f * ev.y;
            ev.z = es.z + sdv.z; ev.z = ev.z > 0.f ? ev.z : 0.2f * ev.z;
            ev.w = es.w + sdv.w; ev.w = ev.w > 0.f ? ev.w : 0.2f * ev.w;
        } else { ev.x = ev.y = ev.z = ev.w = -1e30f; }
        float4 mx = ev;
#pragma unroll
        for (int m = 32; m >= 1; m >>= 1) {
            mx.x = fmaxf(mx.x, __shfl_xor(mx.x, m, 64));
            mx.y = fmaxf(mx.y, __shfl_xor(mx.y, m, 64));
            mx.z = fmaxf(mx.z, __shfl_xor(mx.z, m, 64));
            mx.w = fmaxf(mx.w, __shfl_xor(mx.w, m, 64));
        }
        float4 p;
        p.x = (lane < deg) ? __expf(ev.x - mx.x) : 0.f;
        p.y = (lane < deg) ? __expf(ev.y - mx.y) : 0.f;
        p.z = (lane < deg) ? __expf(ev.z - mx.z) : 0.f;
        p.w = (lane < deg) ? __expf(ev.w - mx.w) : 0.f;
        float4 z = p;
#pragma unroll
        for (int m = 32; m >= 1; m >>= 1) {
            z.x += __shfl_xor(z.x, m, 64);
            z.y += __shfl_xor(z.y, m, 64);
            z.z += __shfl_xor(z.z, m, 64);
            z.w += __shfl_xor(z.w, m, 64);
        }
        float4 alpha;
        alpha.x = p.x / (z.x + 1e-16f);
        alpha.y = p.y / (z.y + 1e-16f);
        alpha.z = p.z / (z.z + 1e-16f);
        alpha.w = p.w / (z.w + 1e-16f);

        *(float4*)&aload[wave][lane][0] = alpha;
        sload[wave][lane] = sreg;
        // wave-private LDS slice: no __syncthreads needed

        int j = 0;
        for (; j + 3 < deg; j += 4) {
            int s0 = sload[wave][j],     s1 = sload[wave][j + 1];
            int s2 = sload[wave][j + 2], s3 = sload[wave][j + 3];
            float a0 = aload[wave][j][hh],     a1 = aload[wave][j + 1][hh];
            float a2 = aload[wave][j + 2][hh], a3 = aload[wave][j + 3][hh];
            bfx8 v0 = *(const bfx8*)(hbuf + (size_t)s0 * 512 + lane * 8);
            bfx8 v1 = *(const bfx8*)(hbuf + (size_t)s1 * 512 + lane * 8);
            bfx8 v2 = *(const bfx8*)(hbuf + (size_t)s2 * 512 + lane * 8);
            bfx8 v3 = *(const bfx8*)(hbuf + (size_t)s3 * 512 + lane * 8);
#pragma unroll
            for (int i = 0; i < 8; i++)
                acc[i] += a0 * bf2f(v0[i]) + a1 * bf2f(v1[i]) +
                          a2 * bf2f(v2[i]) + a3 * bf2f(v3[i]);
        }
        for (; j < deg; j++) {
            int s = sload[wave][j];
            float a = aload[wave][j][hh];
            bfx8 hv = *(const bfx8*)(hbuf + (size_t)s * 512 + lane * 8);
#pragma unroll
            for (int i = 0; i < 8; i++) acc[i] += a * bf2f(hv[i]);
        }
    } else {
        float4 mx; mx.x = mx.y = mx.z = mx.w = -1e30f;
        for (int j = lane; j < deg; j += 64) {
            int s = csr[off + j];
            float4 es = ssrc4[s];
            float4 e;
            e.x = es.x + sdv.x; e.x = e.x > 0.f ? e.x : 0.2f * e.x;
            e.y = es.y + sdv.y; e.y = e.y > 0.f ? e.y : 0.2f * e.y;
            e.z = es.z + sdv.z; e.z = e.z > 0.f ? e.z : 0.2f * e.z;
            e.w = es.w + sdv.w; e.w = e.w > 0.f ? e.w : 0.2f * e.w;
            mx.x = fmaxf(mx.x, e.x); mx.y = fmaxf(mx.y, e.y);
            mx.z = fmaxf(mx.z, e.z); mx.w = fmaxf(mx.w, e.w);
        }
#pragma unroll
        for (int m = 32; m >= 1; m >>= 1) {
            mx.x = fmaxf(mx.x, __shfl_xor(mx.x, m, 64));
            mx.y = fmaxf(mx.y, __shfl_xor(mx.y, m, 64));
            mx.z = fmaxf(mx.z, __shfl_xor(mx.z, m, 64));
            mx.w = fmaxf(mx.w, __shfl_xor(mx.w, m, 64));
        }
        float4 z; z.x = z.y = z.z = z.w = 0.f;
        for (int j = lane; j < deg; j += 64) {
            int s = csr[off + j];
            float4 es = ssrc4[s];
            float4 e;
            e.x = es.x + sdv.x; e.x = e.x > 0.f ? e.x : 0.2f * e.x;
            e.y = es.y + sdv.y; e.y = e.y > 0.f ? e.y : 0.2f * e.y;
            e.z = es.z + sdv.z; e.z = e.z > 0.f ? e.z : 0.2f * e.z;
            e.w = es.w + sdv.w; e.w = e.w > 0.f ? e.w : 0.2f * e.w;
            z.x += __expf(e.x - mx.x); z.y += __expf(e.y - mx.y);
            z.z += __expf(e.z - mx.z); z.w += __expf(e.w - mx.w);
        }
#pragma unroll
        for (int m = 32; m >= 1; m >>= 1) {
            z.x += __shfl_xor(z.x, m, 64);
            z.y += __shfl_xor(z.y, m, 64);
            z.z += __shfl_xor(z.z, m, 64);
            z.w += __shfl_xor(z.w, m, 64);
        }
        float mc = hh == 0 ? mx.x : hh == 1 ? mx.y : hh == 2 ? mx.z : mx.w;
        float zc = hh == 0 ? z.x : hh == 1 ? z.y : hh == 2 ? z.z : z.w;
        float ic = 1.f / (zc + 1e-16f);
        float sdc = hh == 0 ? sdv.x : hh == 1 ? sdv.y : hh == 2 ? sdv.z : sdv.w;
        for (int j = 0; j < deg; j++) {
            int s = csr[off + j];
            float4 es = ssrc4[s];
            float ec = hh == 0 ? es.x : hh == 1 ? es.y : hh == 2 ? es.z : es.w;
            ec += sdc; ec = ec > 0.f ? ec : 0.2f * ec;
            float a = __expf(ec - mc) * ic;
            bfx8 hv = *(const bfx8*)(hbuf + (size_t)s * 512 + lane * 8);
#pragma unroll
            for (int i = 0; i < 8; i++) acc[i] += a * bf2f(hv[i]);
        }
    }

#pragma unroll
    for (int i = 0; i < 8; i++) {
        acc[i] += __shfl_xor(acc[i], 16, 64);
        acc[i] += __shfl_xor(acc[i], 32, 64);
    }
    if (lane < 16) {
        int c0 = lane * 8;
        bfx8 o;
#pragma unroll
        for (int i = 0; i < 8; i++) {
            int c = c0 + i;
            float v = acc[i] * 0.25f + bias[c];
            v = v > 0.f ? v : (__expf(v) - 1.0f);
            float sc = bng[c] * rsqrtf(bnv[c] + 1e-5f);
            v = (v - bnm[c]) * sc + bnb[c];
            o[i] = f2bf(v);
        }
        *(bfx8*)(outb + (size_t)d * 128 + c0) = o;
    }
}

// ---------------- fused softmax + aggregation, layer 3 (H=1) ----------------

__global__ __launch_bounds__(256) void agg1_kernel(const int* __restrict__ offs,
                                                   const int* __restrict__ csr,
                                                   const unsigned short* __restrict__ hbuf1,
                                                   const float* __restrict__ ssrc1,
                                                   const float* __restrict__ sdst1,
                                                   const float* __restrict__ bias,
                                                   float* __restrict__ h3out) {
    __shared__ float aload[4][64];
    __shared__ int sload[4][64];
    int wave = threadIdx.x >> 6, lane = threadIdx.x & 63;
    int d = blockIdx.x * 4 + wave;
    int off = offs[d];
    int deg = offs[d + 1] - off;
    int half = lane >> 5, li = lane & 31;
    float sdv = sdst1[d];
    float acc[4] = {};

    if (deg <= 64) {
        float ev = -1e30f; int sreg = 0;
        if (lane < deg) {
            sreg = csr[off + lane];
            ev = ssrc1[sreg] + sdv;
            ev = ev > 0.f ? ev : 0.2f * ev;
        }
        float mx = ev;
#pragma unroll
        for (int m = 32; m >= 1; m >>= 1) mx = fmaxf(mx, __shfl_xor(mx, m, 64));
        float p = (lane < deg) ? __expf(ev - mx) : 0.f;
        float z = p;
#pragma unroll
        for (int m = 32; m >= 1; m >>= 1) z += __shfl_xor(z, m, 64);
        aload[wave][lane] = p / (z + 1e-16f);
        sload[wave][lane] = sreg;

        int j = half;
        for (; j + 2 < deg; j += 4) {
            int s0 = sload[wave][j], s1 = sload[wave][j + 2];
            float a0 = aload[wave][j], a1 = aload[wave][j + 2];
            bfx4 v0 = *(const bfx4*)(hbuf1 + (size_t)s0 * 128 + li * 4);
            bfx4 v1 = *(const bfx4*)(hbuf1 + (size_t)s1 * 128 + li * 4);
#pragma unroll
            for (int i = 0; i < 4; i++)
                acc[i] += a0 * bf2f(v0[i]) + a1 * bf2f(v1[i]);
        }
        for (; j < deg; j += 2) {
            int s = sload[wave][j];
            float a = aload[wave][j];
            bfx4 hv = *(const bfx4*)(hbuf1 + (size_t)s * 128 + li * 4);
#pragma unroll
            for (int i = 0; i < 4; i++) acc[i] += a * bf2f(hv[i]);
        }
    } else {
        float mx = -1e30f;
        for (int j = lane; j < deg; j += 64) {
            float e = ssrc1[csr[off + j]] + sdv;
            e = e > 0.f ? e : 0.2f * e;
            mx = fmaxf(mx, e);
        }
#pragma unroll
        for (int m = 32; m >= 1; m >>= 1) mx = fmaxf(mx, __shfl_xor(mx, m, 64));
        float z = 0.f;
        for (int j = lane; j < deg; j += 64) {
            float e = ssrc1[csr[off + j]] + sdv;
            e = e > 0.f ? e : 0.2f * e;
            z += __expf(e - mx);
        }
#pragma unroll
        for (int m = 32; m >= 1; m >>= 1) z += __shfl_xor(z, m, 64);
        float inv = 1.f / (z + 1e-16f);
        for (int j = half; j < deg; j += 2) {
            int s = csr[off + j];
            float e = ssrc1[s] + sdv;
            e = e > 0.f ? e : 0.2f * e;
            float a = __expf(e - mx) * inv;
            bfx4 hv = *(const bfx4*)(hbuf1 + (size_t)s * 128 + li * 4);
#pragma unroll
            for (int i = 0; i < 4; i++) acc[i] += a * bf2f(hv[i]);
        }
    }

#pragma unroll
    for (int i = 0; i < 4; i++) acc[i] += __shfl_xor(acc[i], 32, 64);
    if (lane < 32) {
        float4 o;
        o.x = acc[0] + bias[li * 4];
        o.y = acc[1] + bias[li * 4 + 1];
        o.z = acc[2] + bias[li * 4 + 2];
        o.w = acc[3] + bias[li * 4 + 3];
        *(float4*)(h3out + (size_t)d * 128 + li * 4) = o;
    }
}

// ---------------- grouped mean-pool (batch sorted; binary search) ----------------

__global__ __launch_bounds__(256) void pool_kernel(const float* __restrict__ h3,
                                                   const int* __restrict__ batch,
                                                   float* __restrict__ out) {
    __shared__ float red[256];
    int g = blockIdx.x;
    int t = threadIdx.x;
    int lo = 0, n = N_NODES;
    while (n > 0) { int s = n >> 1; if (batch[lo + s] < g) { lo += s + 1; n -= s + 1; } else n = s; }
    int hi = lo; n = N_NODES - lo;
    while (n > 0) { int s = n >> 1; if (batch[hi + s] < g + 1) { hi += s + 1; n -= s + 1; } else n = s; }
    int c = t & 127;
    float acc = 0.f;
    for (int r = lo + (t >> 7); r < hi; r += 2)
        acc += h3[(size_t)r * 128 + c];
    red[t] = acc;
    __syncthreads();
    if (t < 128)
        out[(size_t)g * 128 + t] = (red[t] + red[t + 128]) / fmaxf((float)(hi - lo), 1.0f);
}

// ---------------- host ----------------

extern "C" void kernel_launch(void* const* d_in, const int* in_sizes, int n_in,
                              void* d_out, int out_size, void* d_ws, size_t ws_size,
                              hipStream_t stream) {
    const float* x    = (const float*)d_in[0];
    const int* src    = (const int*)d_in[1];
    const int* dst    = (const int*)d_in[2];
    const int* batch  = (const int*)d_in[3];
    const float* W1   = (const float*)d_in[4];
    const float* as1  = (const float*)d_in[5];
    const float* ad1  = (const float*)d_in[6];
    const float* b1   = (const float*)d_in[7];
    const float* g1   = (const float*)d_in[8];
    const float* be1  = (const float*)d_in[9];
    const float* m1   = (const float*)d_in[10];
    const float* v1   = (const float*)d_in[11];
    const float* W2   = (const float*)d_in[12];
    const float* as2  = (const float*)d_in[13];
    const float* ad2  = (const float*)d_in[14];
    const float* b2   = (const float*)d_in[15];
    const float* g2   = (const float*)d_in[16];
    const float* be2  = (const float*)d_in[17];
    const float* m2   = (const float*)d_in[18];
    const float* v2   = (const float*)d_in[19];
    const float* W3   = (const float*)d_in[20];
    const float* as3  = (const float*)d_in[21];
    const float* ad3  = (const float*)d_in[22];
    const float* b3   = (const float*)d_in[23];
    float* out = (float*)d_out;

    char* w = (char*)d_ws;
    size_t o = 0;
    auto alloc = [&](size_t bytes) -> void* {
        void* p = w + o;
        o += (bytes + 255) & ~(size_t)255;
        return p;
    };
    int* deg     = (int*)alloc((size_t)N_NODES * 4);
    int* offs    = (int*)alloc((size_t)(N_NODES + 1) * 4);
    int* cursor  = (int*)alloc((size_t)N_NODES * 4);
    int* csr     = (int*)alloc((size_t)ETOT * 4);
    float* ssrc  = (float*)alloc((size_t)N_NODES * NHEAD * 4);
    float* sdst  = (float*)alloc((size_t)N_NODES * NHEAD * 4);
    float* h3out = (float*)alloc((size_t)N_NODES * 128 * 4);
    unsigned short* hbuf = (unsigned short*)alloc((size_t)N_NODES * 512 * 2);
    unsigned short* xbuf = (unsigned short*)alloc((size_t)N_NODES * 128 * 2);
    unsigned short* W1t  = (unsigned short*)alloc((size_t)512 * 256 * 2);
    unsigned short* W2t  = (unsigned short*)alloc((size_t)512 * 128 * 2);
    unsigned short* W3t  = (unsigned short*)alloc((size_t)128 * 128 * 2);

    (void)hipMemsetAsync(deg, 0, (size_t)N_NODES * 4, stream);

    // CSR build + weight prep (fused)
    prep_kernel<<<NB_CNT + NB_W1 + NB_W2 + NB_W3, 256, 0, stream>>>(
        dst, deg, W1, W1t, W2, W2t, W3, W3t);
    scan_kernel<<<1, 1024, 0, stream>>>(deg, offs, cursor);
    fill_kernel<<<(ETOT + 255) / 256, 256, 0, stream>>>(src, dst, cursor, csr);

    // ----- layer 1 -----
    mfma_gemm_kernel<256, 4, true><<<N_NODES / 64, 256, 0, stream>>>(
        x, W1t, hbuf, as1, ad1, ssrc, sdst);
    agg4_kernel<<<N_NODES / 4, 256, 0, stream>>>(offs, csr, hbuf, (const float4*)ssrc,
                                                 (const float4*)sdst, b1, g1, be1, m1, v1, xbuf);

    // ----- layer 2 -----
    mfma_gemm_kernel<128, 4, false><<<N_NODES / 64, 256, 0, stream>>>(
        xbuf, W2t, hbuf, as2, ad2, ssrc, sdst);
    agg4_kernel<<<N_NODES / 4, 256, 0, stream>>>(offs, csr, hbuf, (const float4*)ssrc,
                                                 (const float4*)sdst, b2, g2, be2, m2, v2, xbuf);

    // ----- layer 3 -----
    mfma_gemm_kernel<128, 1, false><<<N_NODES / 64, 256, 0, stream>>>(
        xbuf, W3t, hbuf, as3, ad3, ssrc, sdst);
    agg1_kernel<<<N_NODES / 4, 256, 0, stream>>>(offs, csr, hbuf, ssrc, sdst, b3, h3out);

    // ----- grouped mean pool -----
    pool_kernel<<<NG, 256, 0, stream>>>(h3out, batch, out);
}

// Round 10
// 435.471 us; speedup vs baseline: 1.1500x; 1.1500x over previous
//
#include <hip/hip_runtime.h>
#include <cstdint>

#define N_NODES 40000
#define N_EDGES 400000
#define DIN 256
#define DHID 128
#define NG 256
#define NHEAD 4
#define ETOT (N_EDGES + N_NODES)

typedef __attribute__((ext_vector_type(8))) short short8;
typedef __attribute__((ext_vector_type(8))) unsigned short bfx8;
typedef __attribute__((ext_vector_type(4))) unsigned short bfx4;
typedef __attribute__((ext_vector_type(4))) float floatx4;

static __device__ __forceinline__ unsigned short f2bf(float f) {
    unsigned u = __float_as_uint(f);
    unsigned r = (u + 0x7FFFu + ((u >> 16) & 1u)) >> 16;
    return (unsigned short)r;
}
static __device__ __forceinline__ float bf2f(unsigned short s) {
    return __uint_as_float((unsigned)s << 16);
}

// ---------------- fused prep: edge count + 3 weight transposes ----------------
// block ranges: [0,1719) count, then W1t, W2t, W3t

#define NB_CNT 1719
#define NB_W1  512
#define NB_W2  256
#define NB_W3  64

__global__ void prep_kernel(const int* __restrict__ dst, int* __restrict__ deg,
                            const float* __restrict__ W1, unsigned short* __restrict__ W1t,
                            const float* __restrict__ W2, unsigned short* __restrict__ W2t,
                            const float* __restrict__ W3, unsigned short* __restrict__ W3t) {
    int b = blockIdx.x;
    if (b < NB_CNT) {
        int i = b * 256 + threadIdx.x;
        if (i >= ETOT) return;
        int d = (i < N_EDGES) ? dst[i] : (i - N_EDGES);
        atomicAdd(&deg[d], 1);
    } else if (b < NB_CNT + NB_W1) {
        int i = (b - NB_CNT) * 256 + threadIdx.x;       // i < 256*512
        int k = i >> 9, n = i & 511;                     // W1[k*512+n]
        W1t[(size_t)n * 256 + k] = f2bf(W1[i]);
    } else if (b < NB_CNT + NB_W1 + NB_W2) {
        int i = (b - NB_CNT - NB_W1) * 256 + threadIdx.x; // 128*512
        int k = i >> 9, n = i & 511;
        W2t[(size_t)n * 128 + k] = f2bf(W2[i]);
    } else {
        int i = (b - NB_CNT - NB_W1 - NB_W2) * 256 + threadIdx.x; // 128*128
        int k = i >> 7, n = i & 127;
        W3t[(size_t)n * 128 + k] = f2bf(W3[i]);
    }
}

// ---------------- coalesced two-phase scan ----------------

__global__ __launch_bounds__(1024) void scan_kernel(const int* __restrict__ deg,
                                                    int* __restrict__ offs,
                                                    int* __restrict__ cursor) {
    const int IT = 40;                     // 64 lanes * 40 = 2560 per wave
    __shared__ int wsum[16];
    int t = threadIdx.x;
    int lane = t & 63, wv = t >> 6;
    int base = wv * 2560;
    int vals[IT];
    int lsum = 0;
#pragma unroll
    for (int i = 0; i < IT; i++) {
        int idx = base + i * 64 + lane;
        int v = (idx < N_NODES) ? deg[idx] : 0;
        vals[i] = v;
        lsum += v;
    }
#pragma unroll
    for (int m = 32; m >= 1; m >>= 1) lsum += __shfl_xor(lsum, m, 64);
    if (lane == 0) wsum[wv] = lsum;
    __syncthreads();
    if (t == 0) {
        int c = 0;
#pragma unroll
        for (int i = 0; i < 16; i++) { int v = wsum[i]; wsum[i] = c; c += v; }
    }
    __syncthreads();
    int carry = wsum[wv];
#pragma unroll
    for (int i = 0; i < IT; i++) {
        int v = vals[i];
        int inc = v;
#pragma unroll
        for (int off = 1; off < 64; off <<= 1) {
            int n = __shfl_up(inc, off, 64);
            if (lane >= off) inc += n;
        }
        int tot = __shfl(inc, 63, 64);
        int idx = base + i * 64 + lane;
        if (idx < N_NODES) { int o = carry + inc - v; offs[idx] = o; cursor[idx] = o; }
        carry += tot;
    }
    if (t == 0) offs[N_NODES] = ETOT;
}

__global__ void fill_kernel(const int* __restrict__ src, const int* __restrict__ dst,
                            int* __restrict__ cursor, int* __restrict__ csr) {
    int i = blockIdx.x * 256 + threadIdx.x;
    if (i >= ETOT) return;
    int s, d;
    if (i < N_EDGES) { s = src[i]; d = dst[i]; } else { s = d = i - N_EDGES; }
    int pos = atomicAdd(&cursor[d], 1);
    csr[pos] = s;
}

// ---------------- MFMA GEMM (per-head blocks) + fused score epilogue ----------------
// grid (M/64, SH). Block = 64 rows x 128 cols (one head). acc[4][2] -> ~32 acc
// VGPRs, high occupancy. A re-read across heads is absorbed by L3.

template <int K, int NCOL, bool AF32>
__global__ __launch_bounds__(256) void mfma_gemm_kernel(const void* __restrict__ Aptr,
                                                        const unsigned short* __restrict__ Bt,
                                                        unsigned short* __restrict__ C,
                                                        const float* __restrict__ asrc,
                                                        const float* __restrict__ adst,
                                                        float* __restrict__ ssrc,
                                                        float* __restrict__ sdst) {
    constexpr int KC = 128;
    constexpr int KP = KC + 8;
    constexpr int SH = NCOL / 128;
    __shared__ alignas(16) unsigned short A_lds[64][KP];
    __shared__ alignas(16) unsigned short B_lds[128][KP];

    const int tid = threadIdx.x;
    const int lane = tid & 63, wave = tid >> 6;
    const int row0 = blockIdx.x * 64;
    const int head = blockIdx.y;
    const int col0 = head * 128;
    const int cq = lane & 15, rq = lane >> 4;

    floatx4 acc[4][2] = {};

    for (int k0 = 0; k0 < K; k0 += KC) {
        if (k0) __syncthreads();
#pragma unroll
        for (int r = 0; r < 4; r++) {
            int i = r * 256 + tid;
            int row = i >> 4, slot = i & 15;
            if constexpr (AF32) {
                const float* ap = (const float*)Aptr + (size_t)(row0 + row) * K + k0 + slot * 8;
                float4 u0 = *(const float4*)ap;
                float4 u1 = *(const float4*)(ap + 4);
                short8 v;
                v[0] = (short)f2bf(u0.x); v[1] = (short)f2bf(u0.y);
                v[2] = (short)f2bf(u0.z); v[3] = (short)f2bf(u0.w);
                v[4] = (short)f2bf(u1.x); v[5] = (short)f2bf(u1.y);
                v[6] = (short)f2bf(u1.z); v[7] = (short)f2bf(u1.w);
                *(short8*)&A_lds[row][slot * 8] = v;
            } else {
                const unsigned short* ap = (const unsigned short*)Aptr + (size_t)(row0 + row) * K + k0 + slot * 8;
                *(short8*)&A_lds[row][slot * 8] = *(const short8*)ap;
            }
        }
#pragma unroll
        for (int r = 0; r < 8; r++) {
            int i = r * 256 + tid;
            int col = i >> 4, slot = i & 15;
            short8 v = *(const short8*)(Bt + (size_t)(col0 + col) * K + k0 + slot * 8);
            *(short8*)&B_lds[col][slot * 8] = v;
        }
        __syncthreads();

#pragma unroll
        for (int kk = 0; kk < KC; kk += 32) {
            short8 af[4], bfr[2];
#pragma unroll
            for (int i = 0; i < 4; i++)
                af[i] = *(const short8*)&A_lds[i * 16 + cq][kk + rq * 8];
#pragma unroll
            for (int j = 0; j < 2; j++)
                bfr[j] = *(const short8*)&B_lds[wave * 32 + j * 16 + cq][kk + rq * 8];
#pragma unroll
            for (int i = 0; i < 4; i++)
#pragma unroll
                for (int j = 0; j < 2; j++)
                    acc[i][j] = __builtin_amdgcn_mfma_f32_16x16x32_bf16(af[i], bfr[j], acc[i][j], 0, 0, 0);
        }
    }

    // C write (bf16)
#pragma unroll
    for (int i = 0; i < 4; i++)
#pragma unroll
        for (int j = 0; j < 2; j++) {
            unsigned short* cp = C + (size_t)(row0 + i * 16 + rq * 4) * NCOL + col0 + wave * 32 + j * 16 + cq;
#pragma unroll
            for (int r = 0; r < 4; r++)
                cp[(size_t)r * NCOL] = f2bf(acc[i][j][r]);
        }

    // ---- fused score epilogue ----
    const float* ah = asrc + head * 128;
    const float* dh = adst + head * 128;
    float a0 = ah[wave * 32 + cq], a1 = ah[wave * 32 + 16 + cq];
    float d0 = dh[wave * 32 + cq], d1 = dh[wave * 32 + 16 + cq];

    __syncthreads();
    float* sred = (float*)&A_lds[0][0];        // [4][64]
    float* dred = sred + 256;                  // [4][64]

#pragma unroll
    for (int i = 0; i < 4; i++)
#pragma unroll
        for (int r = 0; r < 4; r++) {
            float ss = acc[i][0][r] * a0 + acc[i][1][r] * a1;
            float sd = acc[i][0][r] * d0 + acc[i][1][r] * d1;
#pragma unroll
            for (int m = 1; m <= 8; m <<= 1) {
                ss += __shfl_xor(ss, m, 64);
                sd += __shfl_xor(sd, m, 64);
            }
            if (cq == 0) {
                int row = i * 16 + rq * 4 + r;
                sred[wave * 64 + row] = ss;
                dred[wave * 64 + row] = sd;
            }
        }
    __syncthreads();
    if (tid < 64) {
        float ss = sred[tid] + sred[64 + tid] + sred[128 + tid] + sred[192 + tid];
        float sd = dred[tid] + dred[64 + tid] + dred[128 + tid] + dred[192 + tid];
        ssrc[(size_t)(row0 + tid) * SH + head] = ss;
        sdst[(size_t)(row0 + tid) * SH + head] = sd;
    }
}

// ---------------- fused softmax + aggregation, layer 1/2 (H=4) ----------------
// 1 wave/node, no barriers; inline logits from L2-resident ssrc4; wave-private
// LDS broadcast of alpha/src; 4-wide unrolled 1 KB-row gather.

__global__ __launch_bounds__(256) void agg4_kernel(const int* __restrict__ offs,
                                                   const int* __restrict__ csr,
                                                   const unsigned short* __restrict__ hbuf,
                                                   const float4* __restrict__ ssrc4,
                                                   const float4* __restrict__ sdst4,
                                                   const float* __restrict__ bias,
                                                   const float* __restrict__ bng,
                                                   const float* __restrict__ bnb,
                                                   const float* __restrict__ bnm,
                                                   const float* __restrict__ bnv,
                                                   unsigned short* __restrict__ outb) {
    __shared__ alignas(16) float aload[4][64][4];
    __shared__ int sload[4][64];

    int wave = threadIdx.x >> 6, lane = threadIdx.x & 63;
    int d = blockIdx.x * 4 + wave;
    int off = offs[d];
    int deg = offs[d + 1] - off;
    int hh = lane >> 4;
    float4 sdv = sdst4[d];
    float acc[8] = {};

    if (deg <= 64) {
        int sreg = 0;
        float4 ev;
        if (lane < deg) {
            sreg = csr[off + lane];
            float4 es = ssrc4[sreg];
            ev.x = es.x + sdv.x; ev.x = ev.x > 0.f ? ev.x : 0.2f * ev.x;
            ev.y = es.y + sdv.y; ev.y = ev.y > 0.f ? ev.y : 0.2f * ev.y;
            ev.z = es.z + sdv.z; ev.z = ev.z > 0.f ? ev.z : 0.2f * ev.z;
            ev.w = es.w + sdv.w; ev.w = ev.w > 0.f ? ev.w : 0.2f * ev.w;
        } else { ev.x = ev.y = ev.z = ev.w = -1e30f; }
        float4 mx = ev;
#pragma unroll
        for (int m = 32; m >= 1; m >>= 1) {
            mx.x = fmaxf(mx.x, __shfl_xor(mx.x, m, 64));
            mx.y = fmaxf(mx.y, __shfl_xor(mx.y, m, 64));
            mx.z = fmaxf(mx.z, __shfl_xor(mx.z, m, 64));
            mx.w = fmaxf(mx.w, __shfl_xor(mx.w, m, 64));
        }
        float4 p;
        p.x = (lane < deg) ? __expf(ev.x - mx.x) : 0.f;
        p.y = (lane < deg) ? __expf(ev.y - mx.y) : 0.f;
        p.z = (lane < deg) ? __expf(ev.z - mx.z) : 0.f;
        p.w = (lane < deg) ? __expf(ev.w - mx.w) : 0.f;
        float4 z = p;
#pragma unroll
        for (int m = 32; m >= 1; m >>= 1) {
            z.x += __shfl_xor(z.x, m, 64);
            z.y += __shfl_xor(z.y, m, 64);
            z.z += __shfl_xor(z.z, m, 64);
            z.w += __shfl_xor(z.w, m, 64);
        }
        float4 alpha;
        alpha.x = p.x / (z.x + 1e-16f);
        alpha.y = p.y / (z.y + 1e-16f);
        alpha.z = p.z / (z.z + 1e-16f);
        alpha.w = p.w / (z.w + 1e-16f);

        *(float4*)&aload[wave][lane][0] = alpha;
        sload[wave][lane] = sreg;
        // wave-private LDS slice: no __syncthreads needed

        int j = 0;
        for (; j + 3 < deg; j += 4) {
            int s0 = sload[wave][j],     s1 = sload[wave][j + 1];
            int s2 = sload[wave][j + 2], s3 = sload[wave][j + 3];
            float a0 = aload[wave][j][hh],     a1 = aload[wave][j + 1][hh];
            float a2 = aload[wave][j + 2][hh], a3 = aload[wave][j + 3][hh];
            bfx8 v0 = *(const bfx8*)(hbuf + (size_t)s0 * 512 + lane * 8);
            bfx8 v1 = *(const bfx8*)(hbuf + (size_t)s1 * 512 + lane * 8);
            bfx8 v2 = *(const bfx8*)(hbuf + (size_t)s2 * 512 + lane * 8);
            bfx8 v3 = *(const bfx8*)(hbuf + (size_t)s3 * 512 + lane * 8);
#pragma unroll
            for (int i = 0; i < 8; i++)
                acc[i] += a0 * bf2f(v0[i]) + a1 * bf2f(v1[i]) +
                          a2 * bf2f(v2[i]) + a3 * bf2f(v3[i]);
        }
        for (; j < deg; j++) {
            int s = sload[wave][j];
            float a = aload[wave][j][hh];
            bfx8 hv = *(const bfx8*)(hbuf + (size_t)s * 512 + lane * 8);
#pragma unroll
            for (int i = 0; i < 8; i++) acc[i] += a * bf2f(hv[i]);
        }
    } else {
        float4 mx; mx.x = mx.y = mx.z = mx.w = -1e30f;
        for (int j = lane; j < deg; j += 64) {
            int s = csr[off + j];
            float4 es = ssrc4[s];
            float4 e;
            e.x = es.x + sdv.x; e.x = e.x > 0.f ? e.x : 0.2f * e.x;
            e.y = es.y + sdv.y; e.y = e.y > 0.f ? e.y : 0.2f * e.y;
            e.z = es.z + sdv.z; e.z = e.z > 0.f ? e.z : 0.2f * e.z;
            e.w = es.w + sdv.w; e.w = e.w > 0.f ? e.w : 0.2f * e.w;
            mx.x = fmaxf(mx.x, e.x); mx.y = fmaxf(mx.y, e.y);
            mx.z = fmaxf(mx.z, e.z); mx.w = fmaxf(mx.w, e.w);
        }
#pragma unroll
        for (int m = 32; m >= 1; m >>= 1) {
            mx.x = fmaxf(mx.x, __shfl_xor(mx.x, m, 64));
            mx.y = fmaxf(mx.y, __shfl_xor(mx.y, m, 64));
            mx.z = fmaxf(mx.z, __shfl_xor(mx.z, m, 64));
            mx.w = fmaxf(mx.w, __shfl_xor(mx.w, m, 64));
        }
        float4 z; z.x = z.y = z.z = z.w = 0.f;
        for (int j = lane; j < deg; j += 64) {
            int s = csr[off + j];
            float4 es = ssrc4[s];
            float4 e;
            e.x = es.x + sdv.x; e.x = e.x > 0.f ? e.x : 0.2f * e.x;
            e.y = es.y + sdv.y; e.y = e.y > 0.f ? e.y : 0.2f * e.y;
            e.z = es.z + sdv.z; e.z = e.z > 0.f ? e.z : 0.2f * e.z;
            e.w = es.w + sdv.w; e.w = e.w > 0.f ? e.w : 0.2f * e.w;
            z.x += __expf(e.x - mx.x); z.y += __expf(e.y - mx.y);
            z.z += __expf(e.z - mx.z); z.w += __expf(e.w - mx.w);
        }
#pragma unroll
        for (int m = 32; m >= 1; m >>= 1) {
            z.x += __shfl_xor(z.x, m, 64);
            z.y += __shfl_xor(z.y, m, 64);
            z.z += __shfl_xor(z.z, m, 64);
            z.w += __shfl_xor(z.w, m, 64);
        }
        float mc = hh == 0 ? mx.x : hh == 1 ? mx.y : hh == 2 ? mx.z : mx.w;
        float zc = hh == 0 ? z.x : hh == 1 ? z.y : hh == 2 ? z.z : z.w;
        float ic = 1.f / (zc + 1e-16f);
        float sdc = hh == 0 ? sdv.x : hh == 1 ? sdv.y : hh == 2 ? sdv.z : sdv.w;
        for (int j = 0; j < deg; j++) {
            int s = csr[off + j];
            float4 es = ssrc4[s];
            float ec = hh == 0 ? es.x : hh == 1 ? es.y : hh == 2 ? es.z : es.w;
            ec += sdc; ec = ec > 0.f ? ec : 0.2f * ec;
            float a = __expf(ec - mc) * ic;
            bfx8 hv = *(const bfx8*)(hbuf + (size_t)s * 512 + lane * 8);
#pragma unroll
            for (int i = 0; i < 8; i++) acc[i] += a * bf2f(hv[i]);
        }
    }

#pragma unroll
    for (int i = 0; i < 8; i++) {
        acc[i] += __shfl_xor(acc[i], 16, 64);
        acc[i] += __shfl_xor(acc[i], 32, 64);
    }
    if (lane < 16) {
        int c0 = lane * 8;
        bfx8 o;
#pragma unroll
        for (int i = 0; i < 8; i++) {
            int c = c0 + i;
            float v = acc[i] * 0.25f + bias[c];
            v = v > 0.f ? v : (__expf(v) - 1.0f);
            float sc = bng[c] * rsqrtf(bnv[c] + 1e-5f);
            v = (v - bnm[c]) * sc + bnb[c];
            o[i] = f2bf(v);
        }
        *(bfx8*)(outb + (size_t)d * 128 + c0) = o;
    }
}

// ---------------- fused softmax + aggregation, layer 3 (H=1) ----------------

__global__ __launch_bounds__(256) void agg1_kernel(const int* __restrict__ offs,
                                                   const int* __restrict__ csr,
                                                   const unsigned short* __restrict__ hbuf1,
                                                   const float* __restrict__ ssrc1,
                                                   const float* __restrict__ sdst1,
                                                   const float* __restrict__ bias,
                                                   float* __restrict__ h3out) {
    __shared__ float aload[4][64];
    __shared__ int sload[4][64];
    int wave = threadIdx.x >> 6, lane = threadIdx.x & 63;
    int d = blockIdx.x * 4 + wave;
    int off = offs[d];
    int deg = offs[d + 1] - off;
    int half = lane >> 5, li = lane & 31;
    float sdv = sdst1[d];
    float acc[4] = {};

    if (deg <= 64) {
        float ev = -1e30f; int sreg = 0;
        if (lane < deg) {
            sreg = csr[off + lane];
            ev = ssrc1[sreg] + sdv;
            ev = ev > 0.f ? ev : 0.2f * ev;
        }
        float mx = ev;
#pragma unroll
        for (int m = 32; m >= 1; m >>= 1) mx = fmaxf(mx, __shfl_xor(mx, m, 64));
        float p = (lane < deg) ? __expf(ev - mx) : 0.f;
        float z = p;
#pragma unroll
        for (int m = 32; m >= 1; m >>= 1) z += __shfl_xor(z, m, 64);
        aload[wave][lane] = p / (z + 1e-16f);
        sload[wave][lane] = sreg;

        int j = half;
        for (; j + 2 < deg; j += 4) {
            int s0 = sload[wave][j], s1 = sload[wave][j + 2];
            float a0 = aload[wave][j], a1 = aload[wave][j + 2];
            bfx4 v0 = *(const bfx4*)(hbuf1 + (size_t)s0 * 128 + li * 4);
            bfx4 v1 = *(const bfx4*)(hbuf1 + (size_t)s1 * 128 + li * 4);
#pragma unroll
            for (int i = 0; i < 4; i++)
                acc[i] += a0 * bf2f(v0[i]) + a1 * bf2f(v1[i]);
        }
        for (; j < deg; j += 2) {
            int s = sload[wave][j];
            float a = aload[wave][j];
            bfx4 hv = *(const bfx4*)(hbuf1 + (size_t)s * 128 + li * 4);
#pragma unroll
            for (int i = 0; i < 4; i++) acc[i] += a * bf2f(hv[i]);
        }
    } else {
        float mx = -1e30f;
        for (int j = lane; j < deg; j += 64) {
            float e = ssrc1[csr[off + j]] + sdv;
            e = e > 0.f ? e : 0.2f * e;
            mx = fmaxf(mx, e);
        }
#pragma unroll
        for (int m = 32; m >= 1; m >>= 1) mx = fmaxf(mx, __shfl_xor(mx, m, 64));
        float z = 0.f;
        for (int j = lane; j < deg; j += 64) {
            float e = ssrc1[csr[off + j]] + sdv;
            e = e > 0.f ? e : 0.2f * e;
            z += __expf(e - mx);
        }
#pragma unroll
        for (int m = 32; m >= 1; m >>= 1) z += __shfl_xor(z, m, 64);
        float inv = 1.f / (z + 1e-16f);
        for (int j = half; j < deg; j += 2) {
            int s = csr[off + j];
            float e = ssrc1[s] + sdv;
            e = e > 0.f ? e : 0.2f * e;
            float a = __expf(e - mx) * inv;
            bfx4 hv = *(const bfx4*)(hbuf1 + (size_t)s * 128 + li * 4);
#pragma unroll
            for (int i = 0; i < 4; i++) acc[i] += a * bf2f(hv[i]);
        }
    }

#pragma unroll
    for (int i = 0; i < 4; i++) acc[i] += __shfl_xor(acc[i], 32, 64);
    if (lane < 32) {
        float4 o;
        o.x = acc[0] + bias[li * 4];
        o.y = acc[1] + bias[li * 4 + 1];
        o.z = acc[2] + bias[li * 4 + 2];
        o.w = acc[3] + bias[li * 4 + 3];
        *(float4*)(h3out + (size_t)d * 128 + li * 4) = o;
    }
}

// ---------------- grouped mean-pool (batch sorted; binary search) ----------------

__global__ __launch_bounds__(256) void pool_kernel(const float* __restrict__ h3,
                                                   const int* __restrict__ batch,
                                                   float* __restrict__ out) {
    __shared__ float red[256];
    int g = blockIdx.x;
    int t = threadIdx.x;
    int lo = 0, n = N_NODES;
    while (n > 0) { int s = n >> 1; if (batch[lo + s] < g) { lo += s + 1; n -= s + 1; } else n = s; }
    int hi = lo; n = N_NODES - lo;
    while (n > 0) { int s = n >> 1; if (batch[hi + s] < g + 1) { hi += s + 1; n -= s + 1; } else n = s; }
    int c = t & 127;
    float acc = 0.f;
    for (int r = lo + (t >> 7); r < hi; r += 2)
        acc += h3[(size_t)r * 128 + c];
    red[t] = acc;
    __syncthreads();
    if (t < 128)
        out[(size_t)g * 128 + t] = (red[t] + red[t + 128]) / fmaxf((float)(hi - lo), 1.0f);
}

// ---------------- host ----------------

extern "C" void kernel_launch(void* const* d_in, const int* in_sizes, int n_in,
                              void* d_out, int out_size, void* d_ws, size_t ws_size,
                              hipStream_t stream) {
    const float* x    = (const float*)d_in[0];
    const int* src    = (const int*)d_in[1];
    const int* dst    = (const int*)d_in[2];
    const int* batch  = (const int*)d_in[3];
    const float* W1   = (const float*)d_in[4];
    const float* as1  = (const float*)d_in[5];
    const float* ad1  = (const float*)d_in[6];
    const float* b1   = (const float*)d_in[7];
    const float* g1   = (const float*)d_in[8];
    const float* be1  = (const float*)d_in[9];
    const float* m1   = (const float*)d_in[10];
    const float* v1   = (const float*)d_in[11];
    const float* W2   = (const float*)d_in[12];
    const float* as2  = (const float*)d_in[13];
    const float* ad2  = (const float*)d_in[14];
    const float* b2   = (const float*)d_in[15];
    const float* g2   = (const float*)d_in[16];
    const float* be2  = (const float*)d_in[17];
    const float* m2   = (const float*)d_in[18];
    const float* v2   = (const float*)d_in[19];
    const float* W3   = (const float*)d_in[20];
    const float* as3  = (const float*)d_in[21];
    const float* ad3  = (const float*)d_in[22];
    const float* b3   = (const float*)d_in[23];
    float* out = (float*)d_out;

    char* w = (char*)d_ws;
    size_t o = 0;
    auto alloc = [&](size_t bytes) -> void* {
        void* p = w + o;
        o += (bytes + 255) & ~(size_t)255;
        return p;
    };
    int* deg     = (int*)alloc((size_t)N_NODES * 4);
    int* offs    = (int*)alloc((size_t)(N_NODES + 1) * 4);
    int* cursor  = (int*)alloc((size_t)N_NODES * 4);
    int* csr     = (int*)alloc((size_t)ETOT * 4);
    float* ssrc  = (float*)alloc((size_t)N_NODES * NHEAD * 4);
    float* sdst  = (float*)alloc((size_t)N_NODES * NHEAD * 4);
    float* h3out = (float*)alloc((size_t)N_NODES * 128 * 4);
    unsigned short* hbuf = (unsigned short*)alloc((size_t)N_NODES * 512 * 2);
    unsigned short* xbuf = (unsigned short*)alloc((size_t)N_NODES * 128 * 2);
    unsigned short* W1t  = (unsigned short*)alloc((size_t)512 * 256 * 2);
    unsigned short* W2t  = (unsigned short*)alloc((size_t)512 * 128 * 2);
    unsigned short* W3t  = (unsigned short*)alloc((size_t)128 * 128 * 2);

    (void)hipMemsetAsync(deg, 0, (size_t)N_NODES * 4, stream);

    // CSR build + weight prep (fused)
    prep_kernel<<<NB_CNT + NB_W1 + NB_W2 + NB_W3, 256, 0, stream>>>(
        dst, deg, W1, W1t, W2, W2t, W3, W3t);
    scan_kernel<<<1, 1024, 0, stream>>>(deg, offs, cursor);
    fill_kernel<<<(ETOT + 255) / 256, 256, 0, stream>>>(src, dst, cursor, csr);

    // ----- layer 1 -----
    mfma_gemm_kernel<256, 512, true><<<dim3(N_NODES / 64, 4), 256, 0, stream>>>(
        x, W1t, hbuf, as1, ad1, ssrc, sdst);
    agg4_kernel<<<N_NODES / 4, 256, 0, stream>>>(offs, csr, hbuf, (const float4*)ssrc,
                                                 (const float4*)sdst, b1, g1, be1, m1, v1, xbuf);

    // ----- layer 2 -----
    mfma_gemm_kernel<128, 512, false><<<dim3(N_NODES / 64, 4), 256, 0, stream>>>(
        xbuf, W2t, hbuf, as2, ad2, ssrc, sdst);
    agg4_kernel<<<N_NODES / 4, 256, 0, stream>>>(offs, csr, hbuf, (const float4*)ssrc,
                                                 (const float4*)sdst, b2, g2, be2, m2, v2, xbuf);

    // ----- layer 3 -----
    mfma_gemm_kernel<128, 128, false><<<dim3(N_NODES / 64, 1), 256, 0, stream>>>(
        xbuf, W3t, hbuf, as3, ad3, ssrc, sdst);
    agg1_kernel<<<N_NODES / 4, 256, 0, stream>>>(offs, csr, hbuf, ssrc, sdst, b3, h3out);

    // ----- grouped mean pool -----
    pool_kernel<<<NG, 256, 0, stream>>>(h3out, batch, out);
}